// Round 18
// baseline (184.003 us; speedup 1.0000x reference)
//
#include <hip/hip_runtime.h>

// Problem constants
#define B_DIM   4096
#define IN_DIM  9000
#define OUT_DIM 2048
#define NNZ     200000

// ---- main-path geometry (lane = batch) ----
#define BTILE   256                  // batch rows per block (4 per lane, uint2 gather)
#define B_TILES (B_DIM / BTILE)      // 16
#define COLT_N  64                   // column tiles
#define CPB     (OUT_DIM / COLT_N)   // 32 cols per block
#define THREADS 1024
#define CAP     160                  // bucket capacity: mean 97.7, max~136, 6.3 sigma

typedef float v2f __attribute__((ext_vector_type(2)));

// ---- fallback (R3) geometry ----
#define FB_BTILE  8
#define FB_SEGLEN 1360
#define FB_NSEG   7
#define FB_NKEY   (FB_NSEG * OUT_DIM)  // 14336
#define FB_XPAD   12

// ======================= main path =======================

// Direct bucket scatter. entries[c*CAP + slot] = { r * (B_DIM/4)  (uint2-unit
// gather offset), bits(w) }; cur[c] = count.
__global__ void scatter_direct_kernel(const int* __restrict__ idx,
                                      const float* __restrict__ w,
                                      int* __restrict__ cur,
                                      uint2* __restrict__ entries) {
    int i = blockIdx.x * blockDim.x + threadIdx.x;
    if (i >= NNZ) return;
    int r = idx[2 * i];
    int c = idx[2 * i + 1];
    if ((unsigned)r < IN_DIM && (unsigned)c < OUT_DIM) {
        int slot = atomicAdd(&cur[c], 1);
        if (slot < CAP)
            entries[c * CAP + slot] =
                make_uint2((unsigned)r * (B_DIM / 4), __float_as_uint(w[i]));
    }
}

// x[4096][9000] f32 -> xT[9000][4096] bf16 (RNE), packed as uint (2 bf16/b-pair).
// Block (0,0) also zeroes cur[2048] (runs before scatter in stream order).
__global__ __launch_bounds__(256) void transpose_kernel(const float* __restrict__ x,
                                                        unsigned int* __restrict__ xTu,
                                                        int* __restrict__ cur) {
    __shared__ float tile[64][65];
    int r0 = blockIdx.x * 64;
    int b0 = blockIdx.y * 64;
    int t = threadIdx.x;

    if (blockIdx.x == 0 && blockIdx.y == 0) {
        for (int i = t; i < OUT_DIM; i += 256) cur[i] = 0;
    }

    if (r0 + 64 <= IN_DIM) {            // fast path: full tile, float4 loads
        int j4 = (t & 15) * 4;
        int i0 = t >> 4;                // 0..15
#pragma unroll
        for (int p = 0; p < 4; ++p) {
            int i = i0 + 16 * p;
            float4 v = *(const float4*)&x[(size_t)(b0 + i) * IN_DIM + r0 + j4];
            tile[i][j4 + 0] = v.x;
            tile[i][j4 + 1] = v.y;
            tile[i][j4 + 2] = v.z;
            tile[i][j4 + 3] = v.w;
        }
    } else {                            // edge tile: scalar guarded loads
        int i0 = t >> 6, j = t & 63;
        int r = r0 + j;
#pragma unroll
        for (int ii = 0; ii < 16; ++ii) {
            int i = i0 + 4 * ii;
            tile[i][j] = (r < IN_DIM) ? x[(size_t)(b0 + i) * IN_DIM + r] : 0.f;
        }
    }
    __syncthreads();
    {
        int m  = t & 31;                // b-pair index (b = b0 + 2m, 2m+1)
        int j0 = t >> 5;                // 0..7
#pragma unroll
        for (int p = 0; p < 8; ++p) {
            int jr = j0 + 8 * p;
            int r = r0 + jr;
            if (r < IN_DIM) {
                unsigned int a = __float_as_uint(tile[2 * m][jr]);
                unsigned int b = __float_as_uint(tile[2 * m + 1][jr]);
                unsigned int ha = (a + 0x7fffu + ((a >> 16) & 1u)) >> 16;
                unsigned int hb = (b + 0x7fffu + ((b >> 16) & 1u)) & 0xffff0000u;
                xTu[(size_t)r * (B_DIM / 2) + (b0 >> 1) + m] = ha | hb;
            }
        }
    }
}

// packed FMA over one 8-entry block; 4 b's per lane (uint2 gather), shared
// accumulator banks A[4] (b 4l,4l+1) and B[4] (b 4l+2,4l+3).
#define F8PK2(E, U)                                                       \
    { _Pragma("unroll")                                                   \
      for (int k = 0; k < 8; ++k) {                                       \
          v2f w2 = __uint_as_float(E[k].y);                               \
          v2f ux, uy;                                                     \
          ux.x = __uint_as_float(U[k].x << 16);                           \
          ux.y = __uint_as_float(U[k].x & 0xffff0000u);                   \
          uy.x = __uint_as_float(U[k].y << 16);                           \
          uy.y = __uint_as_float(U[k].y & 0xffff0000u);                   \
          A[k & 3] = __builtin_elementwise_fma(w2, ux, A[k & 3]);         \
          B[k & 3] = __builtin_elementwise_fma(w2, uy, B[k & 3]);         \
      } }

// Main spmm. XCD-sequenced tiles (R8) + dynamic column grab (R9) + 2-deep
// dual-stream pipeline (R11) + uint2 gathers / BTILE=256 (R18): half the
// VMEM instructions per output, same outstanding bytes per wave.
__global__ __launch_bounds__(THREADS, 8) void spmm_xt_kernel(
    const uint2* __restrict__ xTu2,     // xT rows as uint2 (4 bf16), stride B_DIM/4
    const float* __restrict__ bias,
    const int*   __restrict__ cnt,      // per-column entry counts
    const uint2* __restrict__ entries,
    float* __restrict__ out) {

    __shared__ float oacc[CPB * BTILE];     // 32 KB: [col][b ^ (col<<2 & 127)]
    __shared__ int ctr;

    const int t = threadIdx.x;
    const int lane = t & 63;

    if (t == 0) ctr = 0;
    __syncthreads();

    // bid = xcd + 8*colT + 512*group ; b_tile = group*8 + xcd  (bijective)
    const int bid = blockIdx.x;
    const int xcd    = bid & 7;
    const int colT   = (bid >> 3) & 63;
    const int group  = bid >> 9;            // 0..1
    const int b_tile = group * 8 + xcd;

    const int laneoff = b_tile * (BTILE / 4) + lane;   // uint2 offset in a row

    for (;;) {
        int colv = 0;
        if (lane == 0) colv = atomicAdd(&ctr, 1);
        colv = __shfl(colv, 0);
        if (colv >= CPB) break;
        const int col = __builtin_amdgcn_readfirstlane(colv);   // SGPR column
        const int c = colT * CPB + col;
        const int s = c * CAP;
        int n = __builtin_amdgcn_readfirstlane(cnt[c]);
        n = (n > CAP) ? CAP : n;
        const int e = s + n;

        v2f A[4], B[4];
#pragma unroll
        for (int k = 0; k < 4; ++k) { A[k] = (v2f)0.f; B[k] = (v2f)0.f; }

        int jj = s;
        const int nfull = n >> 3;

        if (nfull >= 2) {
            uint2 Ea[8], Eb[8];
            uint2 ua[8];
#pragma unroll
            for (int k = 0; k < 8; ++k) Ea[k] = entries[jj + k];
#pragma unroll
            for (int k = 0; k < 8; ++k) Eb[k] = entries[jj + 8 + k];
#pragma unroll
            for (int k = 0; k < 8; ++k) ua[k] = xTu2[Ea[k].x + laneoff];

            for (int ib = 0; ib < nfull - 2; ++ib) {
                uint2 Ec[8];
#pragma unroll
                for (int k = 0; k < 8; ++k) Ec[k] = entries[jj + 16 + k];
                uint2 ub[8];
#pragma unroll
                for (int k = 0; k < 8; ++k) ub[k] = xTu2[Eb[k].x + laneoff];
                F8PK2(Ea, ua);
#pragma unroll
                for (int k = 0; k < 8; ++k) { Ea[k] = Eb[k]; Eb[k] = Ec[k]; ua[k] = ub[k]; }
                jj += 8;
            }
            // drain: blocks Ea(ua) and Eb remain
            {
                uint2 ub[8];
#pragma unroll
                for (int k = 0; k < 8; ++k) ub[k] = xTu2[Eb[k].x + laneoff];
                F8PK2(Ea, ua);
                F8PK2(Eb, ub);
                jj += 16;
            }
        } else if (nfull == 1) {
            uint2 Ea[8];
            uint2 ua[8];
#pragma unroll
            for (int k = 0; k < 8; ++k) Ea[k] = entries[jj + k];
#pragma unroll
            for (int k = 0; k < 8; ++k) ua[k] = xTu2[Ea[k].x + laneoff];
            F8PK2(Ea, ua);
            jj += 8;
        }
        for (; jj < e; ++jj) {
            uint2 E0 = entries[jj];
            uint2 u0 = xTu2[E0.x + laneoff];
            v2f w2 = __uint_as_float(E0.y);
            v2f ux, uy;
            ux.x = __uint_as_float(u0.x << 16);
            ux.y = __uint_as_float(u0.x & 0xffff0000u);
            uy.x = __uint_as_float(u0.y << 16);
            uy.y = __uint_as_float(u0.y & 0xffff0000u);
            A[0] = __builtin_elementwise_fma(w2, ux, A[0]);
            B[0] = __builtin_elementwise_fma(w2, uy, B[0]);
        }

        v2f S0 = (A[0] + A[1]) + (A[2] + A[3]);   // b = 4l, 4l+1
        v2f S1 = (B[0] + B[1]) + (B[2] + B[3]);   // b = 4l+2, 4l+3

        const int swz = (col & 31) << 2;
        const int b0 = 4 * lane;
        oacc[col * BTILE + ((b0 + 0) ^ swz)] = S0.x;
        oacc[col * BTILE + ((b0 + 1) ^ swz)] = S0.y;
        oacc[col * BTILE + ((b0 + 2) ^ swz)] = S1.x;
        oacc[col * BTILE + ((b0 + 3) ^ swz)] = S1.y;
    }
    __syncthreads();

    // epilogue: coalesced stores, fused bias (lane = consecutive c)
    const int tc = t & 31;                  // c_local
    const int tb = t >> 5;                  // 0..31
    const int C0 = colT * CPB;
    const size_t B0 = (size_t)b_tile * BTILE;
    const float bi = bias[C0 + tc];
    const int swz = (tc & 31) << 2;
#pragma unroll
    for (int bl = 0; bl < BTILE / 32; ++bl) {
        int b = tb + 32 * bl;
        out[(B0 + b) * OUT_DIM + C0 + tc] = oacc[tc * BTILE + (b ^ swz)] + bi;
    }
}

// ======================= fallback path (proven R3) =======================

__global__ void fb_hist_kernel(const int* __restrict__ idx, int* __restrict__ cnt) {
    int i = blockIdx.x * blockDim.x + threadIdx.x;
    if (i >= NNZ) return;
    int r = idx[2 * i];
    int c = idx[2 * i + 1];
    if ((unsigned)r < IN_DIM && (unsigned)c < OUT_DIM) {
        int seg = r / FB_SEGLEN;
        atomicAdd(&cnt[seg * OUT_DIM + c], 1);
    }
}

__global__ __launch_bounds__(1024) void fb_scan_kernel(const int* __restrict__ cnt,
                                                       int* __restrict__ key_start) {
    __shared__ int lds_c[FB_NKEY];
    __shared__ int lds_p[1024];
    int t = threadIdx.x;
    for (int i = t; i < FB_NKEY; i += 1024) lds_c[i] = cnt[i];
    __syncthreads();
    const int CH = FB_NKEY / 1024;
    int base = t * CH;
    int partial = 0;
    for (int i = 0; i < CH; ++i) partial += lds_c[base + i];
    lds_p[t] = partial;
    __syncthreads();
    for (int off = 1; off < 1024; off <<= 1) {
        int v = (t >= off) ? lds_p[t - off] : 0;
        __syncthreads();
        lds_p[t] += v;
        __syncthreads();
    }
    int run = (t == 0) ? 0 : lds_p[t - 1];
    for (int i = 0; i < CH; ++i) { key_start[base + i] = run; run += lds_c[base + i]; }
    if (t == 1023) key_start[FB_NKEY] = lds_p[1023];
}

__global__ void fb_scatter_kernel(const int* __restrict__ idx,
                                  const float* __restrict__ w,
                                  const int* __restrict__ key_start,
                                  int* __restrict__ cur,
                                  uint2* __restrict__ entries) {
    int i = blockIdx.x * blockDim.x + threadIdx.x;
    if (i >= NNZ) return;
    int r = idx[2 * i];
    int c = idx[2 * i + 1];
    if ((unsigned)r < IN_DIM && (unsigned)c < OUT_DIM) {
        int seg = r / FB_SEGLEN;
        int key = seg * OUT_DIM + c;
        int pos = key_start[key] + atomicAdd(&cur[key], 1);
        entries[pos] = make_uint2((unsigned)(r - seg * FB_SEGLEN), __float_as_uint(w[i]));
    }
}

__global__ __launch_bounds__(1024, 8) void fb_spmm_kernel(
    const float* __restrict__ x,
    const float* __restrict__ bias,
    const int*   __restrict__ key_start,
    const uint2* __restrict__ entries,
    float* __restrict__ out) {

    __shared__ float xs[FB_SEGLEN * FB_XPAD];
    const int t = threadIdx.x;
    const size_t b0 = (size_t)blockIdx.x * FB_BTILE;
    const int c0 = t;
    const int c1 = t + 1024;

    float acc0[FB_BTILE], acc1[FB_BTILE];
#pragma unroll
    for (int b = 0; b < FB_BTILE; ++b) { acc0[b] = 0.f; acc1[b] = 0.f; }

    for (int seg = 0; seg < FB_NSEG; ++seg) {
        const int rbase = seg * FB_SEGLEN;
        const int rlen = (IN_DIM - rbase < FB_SEGLEN) ? (IN_DIM - rbase) : FB_SEGLEN;
        __syncthreads();
#pragma unroll
        for (int b = 0; b < FB_BTILE; ++b) {
            const float* __restrict__ src = x + (b0 + b) * IN_DIM + rbase;
            for (int r = t; r < rlen; r += 1024) xs[r * FB_XPAD + b] = src[r];
        }
        __syncthreads();
        for (int cc = 0; cc < 2; ++cc) {
            int c = cc ? c1 : c0;
            float* acc = cc ? acc1 : acc0;
            int s = key_start[seg * OUT_DIM + c];
            int e = key_start[seg * OUT_DIM + c + 1];
            for (int j = s; j < e; ++j) {
                uint2 en = entries[j];
                float wv = __uint_as_float(en.y);
                const float4* xr = (const float4*)(xs + en.x * FB_XPAD);
                float4 lo = xr[0];
                float4 hi = xr[1];
                acc[0] = fmaf(wv, lo.x, acc[0]);
                acc[1] = fmaf(wv, lo.y, acc[1]);
                acc[2] = fmaf(wv, lo.z, acc[2]);
                acc[3] = fmaf(wv, lo.w, acc[3]);
                acc[4] = fmaf(wv, hi.x, acc[4]);
                acc[5] = fmaf(wv, hi.y, acc[5]);
                acc[6] = fmaf(wv, hi.z, acc[6]);
                acc[7] = fmaf(wv, hi.w, acc[7]);
            }
        }
    }
    const float bi0 = bias[c0];
    const float bi1 = bias[c1];
#pragma unroll
    for (int b = 0; b < FB_BTILE; ++b) {
        out[(b0 + b) * OUT_DIM + c0] = acc0[b] + bi0;
        out[(b0 + b) * OUT_DIM + c1] = acc1[b] + bi1;
    }
}

// ======================= launch =======================

extern "C" void kernel_launch(void* const* d_in, const int* in_sizes, int n_in,
                              void* d_out, int out_size, void* d_ws, size_t ws_size,
                              hipStream_t stream) {
    const float* x    = (const float*)d_in[0];
    const int*   idx  = (const int*)  d_in[1];
    const float* w    = (const float*)d_in[2];
    const float* bias = (const float*)d_in[3];
    float* out = (float*)d_out;

    // main-path ws layout: [xT bf16 73.728MB | cur 2048 | pad | entries 2048*CAP*8B]
    const size_t xT_bytes  = (size_t)IN_DIM * B_DIM * 2;          // 73,728,000
    const size_t int_bytes = ((size_t)2048 * 4 + 15) & ~(size_t)15;
    const size_t need = xT_bytes + int_bytes + (size_t)OUT_DIM * CAP * 8;

    if (ws_size >= need) {
        unsigned int* xTu = (unsigned int*)d_ws;
        int* cur       = (int*)((char*)d_ws + xT_bytes);
        uint2* entries = (uint2*)((char*)d_ws + xT_bytes + int_bytes);

        dim3 tg((IN_DIM + 63) / 64, B_DIM / 64);
        transpose_kernel<<<tg, 256, 0, stream>>>(x, xTu, cur);   // also zeroes cur
        scatter_direct_kernel<<<(NNZ + 255) / 256, 256, 0, stream>>>(idx, w, cur, entries);
        spmm_xt_kernel<<<B_TILES * COLT_N, THREADS, 0, stream>>>(
            (const uint2*)xTu, bias, cur, entries, out);
    } else {
        // fallback: proven R3 path (~1.8 MB ws)
        int* cnt       = (int*)d_ws;
        int* cur       = cnt + FB_NKEY;
        int* key_start = cur + FB_NKEY;
        size_t ent_off = ((size_t)(3 * FB_NKEY + 1) * sizeof(int) + 15) & ~(size_t)15;
        uint2* entries = (uint2*)((char*)d_ws + ent_off);

        hipMemsetAsync(cnt, 0, 2 * FB_NKEY * sizeof(int), stream);
        fb_hist_kernel<<<(NNZ + 255) / 256, 256, 0, stream>>>(idx, cnt);
        fb_scan_kernel<<<1, 1024, 0, stream>>>(cnt, key_start);
        fb_scatter_kernel<<<(NNZ + 255) / 256, 256, 0, stream>>>(idx, w, key_start, cur, entries);
        fb_spmm_kernel<<<B_DIM / FB_BTILE, 1024, 0, stream>>>(x, bias, key_start, entries, out);
    }
}

// Round 19
// 176.035 us; speedup vs baseline: 1.0453x; 1.0453x over previous
//
#include <hip/hip_runtime.h>

// Problem constants
#define B_DIM   4096
#define IN_DIM  9000
#define OUT_DIM 2048
#define NNZ     200000

// ---- main-path geometry (lane = batch), R11/R14/R16-proven ----
#define BTILE   128                  // batch rows per block (2 per lane)
#define B_TILES (B_DIM / BTILE)      // 32
#define COLT_N  64                   // column tiles
#define CPB     (OUT_DIM / COLT_N)   // 32 cols per block
#define THREADS 1024
#define CAP     160                  // bucket capacity: mean 97.7, max~136, 6.3 sigma

typedef float v2f __attribute__((ext_vector_type(2)));

// ---- fallback (R3) geometry ----
#define FB_BTILE  8
#define FB_SEGLEN 1360
#define FB_NSEG   7
#define FB_NKEY   (FB_NSEG * OUT_DIM)  // 14336
#define FB_XPAD   12

// ======================= main path =======================

// Direct bucket scatter: no hist, no scan. entries[c*CAP + slot] =
// { r * (B_DIM/2) (pre-scaled gather offset), bits(w) }; cur[c] = count.
__global__ void scatter_direct_kernel(const int* __restrict__ idx,
                                      const float* __restrict__ w,
                                      int* __restrict__ cur,
                                      uint2* __restrict__ entries) {
    int i = blockIdx.x * blockDim.x + threadIdx.x;
    if (i >= NNZ) return;
    int r = idx[2 * i];
    int c = idx[2 * i + 1];
    if ((unsigned)r < IN_DIM && (unsigned)c < OUT_DIM) {
        int slot = atomicAdd(&cur[c], 1);
        if (slot < CAP)
            entries[c * CAP + slot] =
                make_uint2((unsigned)r * (B_DIM / 2), __float_as_uint(w[i]));
    }
}

// x[4096][9000] f32 -> xT[9000][4096] bf16 (RNE), packed as uint (2 bf16/b-pair).
// Block (0,0) also zeroes cur[2048] (runs before scatter in stream order).
__global__ __launch_bounds__(256) void transpose_kernel(const float* __restrict__ x,
                                                        unsigned int* __restrict__ xTu,
                                                        int* __restrict__ cur) {
    __shared__ float tile[64][65];
    int r0 = blockIdx.x * 64;
    int b0 = blockIdx.y * 64;
    int t = threadIdx.x;

    if (blockIdx.x == 0 && blockIdx.y == 0) {
        for (int i = t; i < OUT_DIM; i += 256) cur[i] = 0;
    }

    if (r0 + 64 <= IN_DIM) {            // fast path: full tile, float4 loads
        int j4 = (t & 15) * 4;
        int i0 = t >> 4;                // 0..15
#pragma unroll
        for (int p = 0; p < 4; ++p) {
            int i = i0 + 16 * p;
            float4 v = *(const float4*)&x[(size_t)(b0 + i) * IN_DIM + r0 + j4];
            tile[i][j4 + 0] = v.x;
            tile[i][j4 + 1] = v.y;
            tile[i][j4 + 2] = v.z;
            tile[i][j4 + 3] = v.w;
        }
    } else {                            // edge tile: scalar guarded loads
        int i0 = t >> 6, j = t & 63;
        int r = r0 + j;
#pragma unroll
        for (int ii = 0; ii < 16; ++ii) {
            int i = i0 + 4 * ii;
            tile[i][j] = (r < IN_DIM) ? x[(size_t)(b0 + i) * IN_DIM + r] : 0.f;
        }
    }
    __syncthreads();
    {
        int m  = t & 31;                // b-pair index (b = b0 + 2m, 2m+1)
        int j0 = t >> 5;                // 0..7
#pragma unroll
        for (int p = 0; p < 8; ++p) {
            int jr = j0 + 8 * p;
            int r = r0 + jr;
            if (r < IN_DIM) {
                unsigned int a = __float_as_uint(tile[2 * m][jr]);
                unsigned int b = __float_as_uint(tile[2 * m + 1][jr]);
                unsigned int ha = (a + 0x7fffu + ((a >> 16) & 1u)) >> 16;
                unsigned int hb = (b + 0x7fffu + ((b >> 16) & 1u)) & 0xffff0000u;
                xTu[(size_t)r * (B_DIM / 2) + (b0 >> 1) + m] = ha | hb;
            }
        }
    }
}

// packed FMA over one 8-entry block: A[k] += {w,w} * {lo(u), hi(u)}
#define F8PK(E, U)                                                        \
    { _Pragma("unroll")                                                   \
      for (int k = 0; k < 8; ++k) {                                       \
          v2f w2 = __uint_as_float(E[k].y);                               \
          v2f u2;                                                         \
          u2.x = __uint_as_float(U[k] << 16);                             \
          u2.y = __uint_as_float(U[k] & 0xffff0000u);                     \
          A[k] = __builtin_elementwise_fma(w2, u2, A[k]);                 \
      } }

// Main spmm (R16 structure; inner math v_pk_fma_f32 — R17-proven optimum).
// XCD-sequenced tiles (R8) + dynamic column grab (R9) + 2-deep dual-stream
// software pipeline (R11). Bucket starts implicit (c*CAP).
__global__ __launch_bounds__(THREADS, 8) void spmm_xt_kernel(
    const unsigned int* __restrict__ xTu,   // xT rows as uint (2 bf16), stride B_DIM/2
    const float*        __restrict__ bias,
    const int*          __restrict__ cnt,   // per-column entry counts
    const uint2*        __restrict__ entries,
    float* __restrict__ out) {

    __shared__ float oacc[CPB * BTILE];     // 16 KB: [c_local][b ^ (c&31)]
    __shared__ int ctr;

    const int t = threadIdx.x;
    const int lane = t & 63;

    if (t == 0) ctr = 0;
    __syncthreads();

    // bid = xcd + 8*colT + 512*group ; b_tile = group*8 + xcd  (bijective)
    const int bid = blockIdx.x;
    const int xcd    = bid & 7;
    const int colT   = (bid >> 3) & 63;
    const int group  = bid >> 9;            // 0..3
    const int b_tile = group * 8 + xcd;

    const int laneoff = b_tile * (BTILE / 2) + lane;   // uint offset in a row

    for (;;) {
        int colv = 0;
        if (lane == 0) colv = atomicAdd(&ctr, 1);
        colv = __shfl(colv, 0);
        if (colv >= CPB) break;
        const int col = __builtin_amdgcn_readfirstlane(colv);   // SGPR column
        const int c = colT * CPB + col;
        const int s = c * CAP;
        int n = __builtin_amdgcn_readfirstlane(cnt[c]);
        n = (n > CAP) ? CAP : n;
        const int e = s + n;

        v2f A[8];
#pragma unroll
        for (int k = 0; k < 8; ++k) A[k] = (v2f)0.f;

        int jj = s;
        const int nfull = n >> 3;

        if (nfull >= 2) {
            uint2 Ea[8], Eb[8];
            unsigned int ua[8];
#pragma unroll
            for (int k = 0; k < 8; ++k) Ea[k] = entries[jj + k];
#pragma unroll
            for (int k = 0; k < 8; ++k) Eb[k] = entries[jj + 8 + k];
#pragma unroll
            for (int k = 0; k < 8; ++k) ua[k] = xTu[Ea[k].x + laneoff];

            for (int ib = 0; ib < nfull - 2; ++ib) {
                uint2 Ec[8];
#pragma unroll
                for (int k = 0; k < 8; ++k) Ec[k] = entries[jj + 16 + k];
                unsigned int ub[8];
#pragma unroll
                for (int k = 0; k < 8; ++k) ub[k] = xTu[Eb[k].x + laneoff];
                F8PK(Ea, ua);
#pragma unroll
                for (int k = 0; k < 8; ++k) { Ea[k] = Eb[k]; Eb[k] = Ec[k]; ua[k] = ub[k]; }
                jj += 8;
            }
            // drain: blocks Ea(ua) and Eb remain
            {
                unsigned int ub[8];
#pragma unroll
                for (int k = 0; k < 8; ++k) ub[k] = xTu[Eb[k].x + laneoff];
                F8PK(Ea, ua);
                F8PK(Eb, ub);
                jj += 16;
            }
        } else if (nfull == 1) {
            uint2 Ea[8];
            unsigned int ua[8];
#pragma unroll
            for (int k = 0; k < 8; ++k) Ea[k] = entries[jj + k];
#pragma unroll
            for (int k = 0; k < 8; ++k) ua[k] = xTu[Ea[k].x + laneoff];
            F8PK(Ea, ua);
            jj += 8;
        }
        for (; jj < e; ++jj) {
            uint2 E0 = entries[jj];
            unsigned int u0 = xTu[E0.x + laneoff];
            v2f w2 = __uint_as_float(E0.y);
            v2f u2;
            u2.x = __uint_as_float(u0 << 16);
            u2.y = __uint_as_float(u0 & 0xffff0000u);
            A[0] = __builtin_elementwise_fma(w2, u2, A[0]);
        }

        v2f S = ((A[0] + A[1]) + (A[2] + A[3])) + ((A[4] + A[5]) + (A[6] + A[7]));

        const int bl0 = 2 * lane;
        oacc[col * BTILE + (bl0 ^ (col & 31))]       = S.x;
        oacc[col * BTILE + ((bl0 + 1) ^ (col & 31))] = S.y;
    }
    __syncthreads();

    // epilogue: coalesced stores, fused bias (lane = consecutive c)
    const int tc = t & 31;                  // c_local
    const int tb = t >> 5;                  // 0..31
    const int C0 = colT * CPB;
    const size_t B0 = (size_t)b_tile * BTILE;
    const float bi = bias[C0 + tc];
#pragma unroll
    for (int bl = 0; bl < BTILE / 32; ++bl) {
        int b = tb + 32 * bl;
        out[(B0 + b) * OUT_DIM + C0 + tc] = oacc[tc * BTILE + (b ^ (tc & 31))] + bi;
    }
}

// ======================= fallback path (proven R3) =======================

__global__ void fb_hist_kernel(const int* __restrict__ idx, int* __restrict__ cnt) {
    int i = blockIdx.x * blockDim.x + threadIdx.x;
    if (i >= NNZ) return;
    int r = idx[2 * i];
    int c = idx[2 * i + 1];
    if ((unsigned)r < IN_DIM && (unsigned)c < OUT_DIM) {
        int seg = r / FB_SEGLEN;
        atomicAdd(&cnt[seg * OUT_DIM + c], 1);
    }
}

__global__ __launch_bounds__(1024) void fb_scan_kernel(const int* __restrict__ cnt,
                                                       int* __restrict__ key_start) {
    __shared__ int lds_c[FB_NKEY];
    __shared__ int lds_p[1024];
    int t = threadIdx.x;
    for (int i = t; i < FB_NKEY; i += 1024) lds_c[i] = cnt[i];
    __syncthreads();
    const int CH = FB_NKEY / 1024;
    int base = t * CH;
    int partial = 0;
    for (int i = 0; i < CH; ++i) partial += lds_c[base + i];
    lds_p[t] = partial;
    __syncthreads();
    for (int off = 1; off < 1024; off <<= 1) {
        int v = (t >= off) ? lds_p[t - off] : 0;
        __syncthreads();
        lds_p[t] += v;
        __syncthreads();
    }
    int run = (t == 0) ? 0 : lds_p[t - 1];
    for (int i = 0; i < CH; ++i) { key_start[base + i] = run; run += lds_c[base + i]; }
    if (t == 1023) key_start[FB_NKEY] = lds_p[1023];
}

__global__ void fb_scatter_kernel(const int* __restrict__ idx,
                                  const float* __restrict__ w,
                                  const int* __restrict__ key_start,
                                  int* __restrict__ cur,
                                  uint2* __restrict__ entries) {
    int i = blockIdx.x * blockDim.x + threadIdx.x;
    if (i >= NNZ) return;
    int r = idx[2 * i];
    int c = idx[2 * i + 1];
    if ((unsigned)r < IN_DIM && (unsigned)c < OUT_DIM) {
        int seg = r / FB_SEGLEN;
        int key = seg * OUT_DIM + c;
        int pos = key_start[key] + atomicAdd(&cur[key], 1);
        entries[pos] = make_uint2((unsigned)(r - seg * FB_SEGLEN), __float_as_uint(w[i]));
    }
}

__global__ __launch_bounds__(1024, 8) void fb_spmm_kernel(
    const float* __restrict__ x,
    const float* __restrict__ bias,
    const int*   __restrict__ key_start,
    const uint2* __restrict__ entries,
    float* __restrict__ out) {

    __shared__ float xs[FB_SEGLEN * FB_XPAD];
    const int t = threadIdx.x;
    const size_t b0 = (size_t)blockIdx.x * FB_BTILE;
    const int c0 = t;
    const int c1 = t + 1024;

    float acc0[FB_BTILE], acc1[FB_BTILE];
#pragma unroll
    for (int b = 0; b < FB_BTILE; ++b) { acc0[b] = 0.f; acc1[b] = 0.f; }

    for (int seg = 0; seg < FB_NSEG; ++seg) {
        const int rbase = seg * FB_SEGLEN;
        const int rlen = (IN_DIM - rbase < FB_SEGLEN) ? (IN_DIM - rbase) : FB_SEGLEN;
        __syncthreads();
#pragma unroll
        for (int b = 0; b < FB_BTILE; ++b) {
            const float* __restrict__ src = x + (b0 + b) * IN_DIM + rbase;
            for (int r = t; r < rlen; r += 1024) xs[r * FB_XPAD + b] = src[r];
        }
        __syncthreads();
        for (int cc = 0; cc < 2; ++cc) {
            int c = cc ? c1 : c0;
            float* acc = cc ? acc1 : acc0;
            int s = key_start[seg * OUT_DIM + c];
            int e = key_start[seg * OUT_DIM + c + 1];
            for (int j = s; j < e; ++j) {
                uint2 en = entries[j];
                float wv = __uint_as_float(en.y);
                const float4* xr = (const float4*)(xs + en.x * FB_XPAD);
                float4 lo = xr[0];
                float4 hi = xr[1];
                acc[0] = fmaf(wv, lo.x, acc[0]);
                acc[1] = fmaf(wv, lo.y, acc[1]);
                acc[2] = fmaf(wv, lo.z, acc[2]);
                acc[3] = fmaf(wv, lo.w, acc[3]);
                acc[4] = fmaf(wv, hi.x, acc[4]);
                acc[5] = fmaf(wv, hi.y, acc[5]);
                acc[6] = fmaf(wv, hi.z, acc[6]);
                acc[7] = fmaf(wv, hi.w, acc[7]);
            }
        }
    }
    const float bi0 = bias[c0];
    const float bi1 = bias[c1];
#pragma unroll
    for (int b = 0; b < FB_BTILE; ++b) {
        out[(b0 + b) * OUT_DIM + c0] = acc0[b] + bi0;
        out[(b0 + b) * OUT_DIM + c1] = acc1[b] + bi1;
    }
}

// ======================= launch =======================

extern "C" void kernel_launch(void* const* d_in, const int* in_sizes, int n_in,
                              void* d_out, int out_size, void* d_ws, size_t ws_size,
                              hipStream_t stream) {
    const float* x    = (const float*)d_in[0];
    const int*   idx  = (const int*)  d_in[1];
    const float* w    = (const float*)d_in[2];
    const float* bias = (const float*)d_in[3];
    float* out = (float*)d_out;

    // main-path ws layout: [xT bf16 73.728MB | cur 2048 | pad | entries 2048*CAP*8B]
    const size_t xT_bytes  = (size_t)IN_DIM * B_DIM * 2;          // 73,728,000
    const size_t int_bytes = ((size_t)2048 * 4 + 15) & ~(size_t)15;
    const size_t need = xT_bytes + int_bytes + (size_t)OUT_DIM * CAP * 8;

    if (ws_size >= need) {
        unsigned int* xTu = (unsigned int*)d_ws;
        int* cur       = (int*)((char*)d_ws + xT_bytes);
        uint2* entries = (uint2*)((char*)d_ws + xT_bytes + int_bytes);

        dim3 tg((IN_DIM + 63) / 64, B_DIM / 64);
        transpose_kernel<<<tg, 256, 0, stream>>>(x, xTu, cur);   // also zeroes cur
        scatter_direct_kernel<<<(NNZ + 255) / 256, 256, 0, stream>>>(idx, w, cur, entries);
        spmm_xt_kernel<<<B_TILES * COLT_N, THREADS, 0, stream>>>(
            xTu, bias, cur, entries, out);
    } else {
        // fallback: proven R3 path (~1.8 MB ws)
        int* cnt       = (int*)d_ws;
        int* cur       = cnt + FB_NKEY;
        int* key_start = cur + FB_NKEY;
        size_t ent_off = ((size_t)(3 * FB_NKEY + 1) * sizeof(int) + 15) & ~(size_t)15;
        uint2* entries = (uint2*)((char*)d_ws + ent_off);

        hipMemsetAsync(cnt, 0, 2 * FB_NKEY * sizeof(int), stream);
        fb_hist_kernel<<<(NNZ + 255) / 256, 256, 0, stream>>>(idx, cnt);
        fb_scan_kernel<<<1, 1024, 0, stream>>>(cnt, key_start);
        fb_scatter_kernel<<<(NNZ + 255) / 256, 256, 0, stream>>>(idx, w, key_start, cur, entries);
        fb_spmm_kernel<<<B_DIM / FB_BTILE, 1024, 0, stream>>>(x, bias, key_start, entries, out);
    }
}